// Round 1
// baseline (27057.318 us; speedup 1.0000x reference)
//
#include <hip/hip_runtime.h>

#define FF 512
#define HH 1024
#define LL 128
#define BB 128
#define PP 1024

__device__ __forceinline__ float sigm(float x) {
    return 1.0f / (1.0f + __expf(-x));
}
// overflow-safe tanh: exp(-2|x|) underflows to 0 for large |x| -> +-1
__device__ __forceinline__ float tanh_fast(float x) {
    float ax = fabsf(x);
    float e = __expf(-2.0f * ax);
    float r = (1.0f - e) / (1.0f + e);
    return copysignf(r, x);
}

__global__ void fillz(float* p, int n) {
    int i = blockIdx.x * blockDim.x + threadIdx.x;
    if (i < n) p[i] = 0.0f;
}

// ---------------------------------------------------------------------------
// LSTM step: g[f][gc] = init[f][gc] + sum_k h_in[f][k] * W_hh[gc][k]
// then cell update (masked by t < lengths[f] when lengths != null).
// init source: embW[tokens[f][t]] (encoder) or u_p[f] (decoder, tokens==null).
// grid (8, 32): 64 f-rows x 32 h-cols (x4 gates) per block; 256 threads.
// Each thread: 4 rows x (2 cols x 4 gates) = 32 accumulators -> owns the full
// cell update for 4x2 (f, h-col) pairs.
// ---------------------------------------------------------------------------
__global__ __launch_bounds__(256) void lstm_step(
    const float* __restrict__ h_in,
    float* __restrict__ h_out,
    float* __restrict__ c_st,
    const float* __restrict__ W_hh,    // [4096][1024]
    const float* __restrict__ initE,   // embW [128][4096] or u_p [512][4096]
    const int* __restrict__ tokens,    // [512][128] or null
    const int* __restrict__ lengths,   // [512] or null
    int t)
{
    __shared__ __align__(16) float As[32][64];    // [k][m]
    __shared__ __align__(16) float Bs[32][128];   // [k][gate*32+c]

    const int tid = threadIdx.x;
    const int tm = tid & 15;          // row group 0..15 (4 rows each)
    const int tn = tid >> 4;          // col group 0..15 (2 cols each)
    const int fbase = blockIdx.x * 64;
    const int n0 = blockIdx.y * 32;

    // staging maps
    const int am  = tid >> 2;         // 0..63   (A row within tile)
    const int akq = (tid & 3) * 8;    // k sub-offset 0,8,16,24
    const int br  = tid >> 1;         // 0..127  (B row within tile)
    const int bkh = (tid & 1) * 16;   // k sub-offset 0,16
    const int bgate = br >> 5;
    const int bcol  = br & 31;
    const float* arow = h_in + (size_t)(fbase + am) * HH;
    const float* brow = W_hh + (size_t)(bgate * HH + n0 + bcol) * HH;

    float acc[4][4][2];
    #pragma unroll
    for (int a = 0; a < 4; ++a)
        #pragma unroll
        for (int g = 0; g < 4; ++g) { acc[a][g][0] = 0.f; acc[a][g][1] = 0.f; }

    // prefetch chunk 0 into registers
    float4 pa0 = *(const float4*)(arow + akq);
    float4 pa1 = *(const float4*)(arow + akq + 4);
    float4 pb0 = *(const float4*)(brow + bkh);
    float4 pb1 = *(const float4*)(brow + bkh + 4);
    float4 pb2 = *(const float4*)(brow + bkh + 8);
    float4 pb3 = *(const float4*)(brow + bkh + 12);

    const int tm4 = tm * 4;
    const int tn2 = tn * 2;

    for (int kc = 0; kc < 32; ++kc) {
        __syncthreads();
        As[akq + 0][am] = pa0.x; As[akq + 1][am] = pa0.y;
        As[akq + 2][am] = pa0.z; As[akq + 3][am] = pa0.w;
        As[akq + 4][am] = pa1.x; As[akq + 5][am] = pa1.y;
        As[akq + 6][am] = pa1.z; As[akq + 7][am] = pa1.w;
        Bs[bkh +  0][br] = pb0.x; Bs[bkh +  1][br] = pb0.y;
        Bs[bkh +  2][br] = pb0.z; Bs[bkh +  3][br] = pb0.w;
        Bs[bkh +  4][br] = pb1.x; Bs[bkh +  5][br] = pb1.y;
        Bs[bkh +  6][br] = pb1.z; Bs[bkh +  7][br] = pb1.w;
        Bs[bkh +  8][br] = pb2.x; Bs[bkh +  9][br] = pb2.y;
        Bs[bkh + 10][br] = pb2.z; Bs[bkh + 11][br] = pb2.w;
        Bs[bkh + 12][br] = pb3.x; Bs[bkh + 13][br] = pb3.y;
        Bs[bkh + 14][br] = pb3.z; Bs[bkh + 15][br] = pb3.w;
        __syncthreads();

        if (kc < 31) {  // prefetch next chunk; latency hidden by FMA loop
            const int k0 = (kc + 1) * 32;
            pa0 = *(const float4*)(arow + k0 + akq);
            pa1 = *(const float4*)(arow + k0 + akq + 4);
            pb0 = *(const float4*)(brow + k0 + bkh);
            pb1 = *(const float4*)(brow + k0 + bkh + 4);
            pb2 = *(const float4*)(brow + k0 + bkh + 8);
            pb3 = *(const float4*)(brow + k0 + bkh + 12);
        }

        #pragma unroll
        for (int k = 0; k < 32; ++k) {
            float4 a = *(const float4*)&As[k][tm4];
            #pragma unroll
            for (int g = 0; g < 4; ++g) {
                float2 b = *(const float2*)&Bs[k][g * 32 + tn2];
                acc[0][g][0] += a.x * b.x; acc[0][g][1] += a.x * b.y;
                acc[1][g][0] += a.y * b.x; acc[1][g][1] += a.y * b.y;
                acc[2][g][0] += a.z * b.x; acc[2][g][1] += a.z * b.y;
                acc[3][g][0] += a.w * b.x; acc[3][g][1] += a.w * b.y;
            }
        }
    }

    const int hc = n0 + tn2;
    #pragma unroll
    for (int mi = 0; mi < 4; ++mi) {
        const int f = fbase + tm4 + mi;
        const float* ib = tokens ? (initE + (size_t)tokens[f * LL + t] * 4096)
                                 : (initE + (size_t)f * 4096);
        float gi0 = acc[mi][0][0] + ib[hc];
        float gi1 = acc[mi][0][1] + ib[hc + 1];
        float gf0 = acc[mi][1][0] + ib[1024 + hc];
        float gf1 = acc[mi][1][1] + ib[1024 + hc + 1];
        float gg0 = acc[mi][2][0] + ib[2048 + hc];
        float gg1 = acc[mi][2][1] + ib[2048 + hc + 1];
        float go0 = acc[mi][3][0] + ib[3072 + hc];
        float go1 = acc[mi][3][1] + ib[3072 + hc + 1];

        float2 cold = *(const float2*)(c_st + (size_t)f * HH + hc);
        float2 hold = *(const float2*)(h_in + (size_t)f * HH + hc);

        float cn0 = sigm(gf0) * cold.x + sigm(gi0) * tanh_fast(gg0);
        float cn1 = sigm(gf1) * cold.y + sigm(gi1) * tanh_fast(gg1);
        float hn0 = sigm(go0) * tanh_fast(cn0);
        float hn1 = sigm(go1) * tanh_fast(cn1);

        bool upd = lengths ? (t < lengths[f]) : true;
        float2 cw, hw;
        cw.x = upd ? cn0 : cold.x; cw.y = upd ? cn1 : cold.y;
        hw.x = upd ? hn0 : hold.x; hw.y = upd ? hn1 : hold.y;
        *(float2*)(c_st + (size_t)f * HH + hc) = cw;
        *(float2*)(h_out + (size_t)f * HH + hc) = hw;
    }
}

// ---------------------------------------------------------------------------
// Generic C[M][N] = A[M][K] @ W[N][K]^T + bias[N]
// grid (M/32, N/64), block 256; per thread 4x2.
// ---------------------------------------------------------------------------
__global__ __launch_bounds__(256) void gemm_bias(
    const float* __restrict__ A, const float* __restrict__ W,
    const float* __restrict__ bias, float* __restrict__ C,
    int N, int K)
{
    __shared__ __align__(16) float As[16][32];
    __shared__ __align__(16) float Bs[16][64];
    const int tid = threadIdx.x;
    const int tm = tid & 7;
    const int tn = tid >> 3;
    const int m0 = blockIdx.x * 32, n0 = blockIdx.y * 64;
    const int am = tid >> 3;          // 0..31
    const int ak = (tid & 7) * 2;     // 0..14
    const int br = tid >> 2;          // 0..63
    const int bk = (tid & 3) * 4;     // 0,4,8,12
    const float* arow = A + (size_t)(m0 + am) * K;
    const float* brow = W + (size_t)(n0 + br) * K;
    float acc[4][2] = {};
    const int tm4 = tm * 4, tn2 = tn * 2;

    for (int k0 = 0; k0 < K; k0 += 16) {
        __syncthreads();
        float2 av = *(const float2*)(arow + k0 + ak);
        float4 bv = *(const float4*)(brow + k0 + bk);
        As[ak][am] = av.x; As[ak + 1][am] = av.y;
        Bs[bk][br] = bv.x; Bs[bk + 1][br] = bv.y;
        Bs[bk + 2][br] = bv.z; Bs[bk + 3][br] = bv.w;
        __syncthreads();
        #pragma unroll
        for (int k = 0; k < 16; ++k) {
            float4 a = *(const float4*)&As[k][tm4];
            float2 b = *(const float2*)&Bs[k][tn2];
            acc[0][0] += a.x * b.x; acc[0][1] += a.x * b.y;
            acc[1][0] += a.y * b.x; acc[1][1] += a.y * b.y;
            acc[2][0] += a.z * b.x; acc[2][1] += a.z * b.y;
            acc[3][0] += a.w * b.x; acc[3][1] += a.w * b.y;
        }
    }
    float b0 = bias[n0 + tn2], b1 = bias[n0 + tn2 + 1];
    #pragma unroll
    for (int mi = 0; mi < 4; ++mi) {
        float2 o;
        o.x = acc[mi][0] + b0;
        o.y = acc[mi][1] + b1;
        *(float2*)(C + (size_t)(m0 + tm4 + mi) * N + n0 + tn2) = o;
    }
}

// ---------------------------------------------------------------------------
// pooled[b][n] = max_e tanh(h[4b+e] @ W_mp^T + b_mp)   (tanh monotone ->
// tanh of max). grid (16,16), block 256; thread's 4 rows = one program b.
// ---------------------------------------------------------------------------
__global__ __launch_bounds__(256) void mp_pool(
    const float* __restrict__ h, const float* __restrict__ Wmp,
    const float* __restrict__ bmp, float* __restrict__ pooled)
{
    __shared__ __align__(16) float As[16][32];
    __shared__ __align__(16) float Bs[16][64];
    const int tid = threadIdx.x;
    const int tm = tid & 7;
    const int tn = tid >> 3;
    const int m0 = blockIdx.x * 32, n0 = blockIdx.y * 64;
    const int am = tid >> 3;
    const int ak = (tid & 7) * 2;
    const int br = tid >> 2;
    const int bk = (tid & 3) * 4;
    const float* arow = h + (size_t)(m0 + am) * HH;
    const float* brow = Wmp + (size_t)(n0 + br) * HH;
    float acc[4][2] = {};
    const int tm4 = tm * 4, tn2 = tn * 2;

    for (int k0 = 0; k0 < HH; k0 += 16) {
        __syncthreads();
        float2 av = *(const float2*)(arow + k0 + ak);
        float4 bv = *(const float4*)(brow + k0 + bk);
        As[ak][am] = av.x; As[ak + 1][am] = av.y;
        Bs[bk][br] = bv.x; Bs[bk + 1][br] = bv.y;
        Bs[bk + 2][br] = bv.z; Bs[bk + 3][br] = bv.w;
        __syncthreads();
        #pragma unroll
        for (int k = 0; k < 16; ++k) {
            float4 a = *(const float4*)&As[k][tm4];
            float2 b = *(const float2*)&Bs[k][tn2];
            acc[0][0] += a.x * b.x; acc[0][1] += a.x * b.y;
            acc[1][0] += a.y * b.x; acc[1][1] += a.y * b.y;
            acc[2][0] += a.z * b.x; acc[2][1] += a.z * b.y;
            acc[3][0] += a.w * b.x; acc[3][1] += a.w * b.y;
        }
    }
    float mx0 = fmaxf(fmaxf(acc[0][0], acc[1][0]), fmaxf(acc[2][0], acc[3][0]));
    float mx1 = fmaxf(fmaxf(acc[0][1], acc[1][1]), fmaxf(acc[2][1], acc[3][1]));
    mx0 += bmp[n0 + tn2];
    mx1 += bmp[n0 + tn2 + 1];
    float2 o;
    o.x = tanh_fast(mx0);
    o.y = tanh_fast(mx1);
    const int bidx = (m0 >> 2) + tm;  // rows m0+tm*4..+3 = program bidx
    *(float2*)(pooled + (size_t)bidx * HH + n0 + tn2) = o;
}

extern "C" void kernel_launch(void* const* d_in, const int* in_sizes, int n_in,
                              void* d_out, int out_size, void* d_ws, size_t ws_size,
                              hipStream_t stream)
{
    const int*   tokens_in   = (const int*)d_in[0];
    const int*   lengths_in  = (const int*)d_in[1];
    const int*   tokens_out  = (const int*)d_in[2];
    const int*   lengths_out = (const int*)d_in[3];
    const float* embedding   = (const float*)d_in[4];
    const float* W_ih_in     = (const float*)d_in[5];
    const float* W_hh_in     = (const float*)d_in[6];
    const float* b_in        = (const float*)d_in[7];
    const float* W_ih_out    = (const float*)d_in[8];
    const float* W_hh_out    = (const float*)d_in[9];
    const float* b_out       = (const float*)d_in[10];
    const float* W_ih_p      = (const float*)d_in[11];
    const float* W_hh_p      = (const float*)d_in[12];
    const float* b_p         = (const float*)d_in[13];
    const float* W_mp        = (const float*)d_in[14];
    const float* b_mp        = (const float*)d_in[15];
    const float* W_sm        = (const float*)d_in[16];
    const float* b_sm        = (const float*)d_in[17];
    float* out = (float*)d_out;

    float* ws = (float*)d_ws;
    float* h_a      = ws;                 // 524288 floats
    float* c_st     = ws + 524288;        // 524288
    float* h_b      = ws + 1048576;       // 524288
    float* embW_in  = ws + 1572864;       // 524288 (128 x 4096)
    float* embW_out = ws + 2097152;       // 524288
    float* u_p      = ws + 2621440;       // 2097152 (512 x 4096)
    float* pooled   = ws + 4718592;       // 131072 (128 x 1024)

    // h0 = c0 = 0 (ws is poisoned before every call); h_a and c are adjacent.
    fillz<<<2048, 512, 0, stream>>>(h_a, 1048576);

    // embW = embedding @ W_ih^T + b  (the x@W_ih GEMM collapses to a gather)
    gemm_bias<<<dim3(4, 64), 256, 0, stream>>>(embedding, W_ih_in, b_in, embW_in, 4096, 128);
    gemm_bias<<<dim3(4, 64), 256, 0, stream>>>(embedding, W_ih_out, b_out, embW_out, 4096, 128);

    float* hc = h_a;
    float* hn = h_b;
    for (int t = 0; t < 128; ++t) {
        lstm_step<<<dim3(8, 32), 256, 0, stream>>>(hc, hn, c_st, W_hh_in, embW_in,
                                                   tokens_in, lengths_in, t);
        float* tmp = hc; hc = hn; hn = tmp;
    }
    for (int t = 0; t < 128; ++t) {
        lstm_step<<<dim3(8, 32), 256, 0, stream>>>(hc, hn, c_st, W_hh_out, embW_out,
                                                   tokens_out, lengths_out, t);
        float* tmp = hc; hc = hn; hn = tmp;
    }

    // u_p = prev_h @ W_ih_p^T + b_p  (prev_h constant across all 16 steps)
    gemm_bias<<<dim3(16, 64), 256, 0, stream>>>(hc, W_ih_p, b_p, u_p, 4096, 1024);

    for (int t = 0; t < 16; ++t) {
        lstm_step<<<dim3(8, 32), 256, 0, stream>>>(hc, hn, c_st, W_hh_p, u_p,
                                                   nullptr, nullptr, t);
        mp_pool<<<dim3(16, 16), 256, 0, stream>>>(hn, W_mp, b_mp, pooled);
        gemm_bias<<<dim3(4, 16), 256, 0, stream>>>(pooled, W_sm, b_sm,
                                                   out + (size_t)t * (BB * PP), 1024, 1024);
        float* tmp = hc; hc = hn; hn = tmp;
    }
}

// Round 2
// 11208.018 us; speedup vs baseline: 2.4141x; 2.4141x over previous
//
#include <hip/hip_runtime.h>

#define FF 512
#define HH 1024
#define LL 128
#define BB 128
#define PP 1024

typedef short short8 __attribute__((ext_vector_type(8)));
typedef float floatx4 __attribute__((ext_vector_type(4)));
typedef unsigned short ushort_t;

__device__ __forceinline__ float sigm(float x) {
    return 1.0f / (1.0f + __expf(-x));
}
// overflow-safe tanh: exp(-2|x|) underflows to 0 for large |x| -> +-1
__device__ __forceinline__ float tanh_fast(float x) {
    float ax = fabsf(x);
    float e = __expf(-2.0f * ax);
    float r = (1.0f - e) / (1.0f + e);
    return copysignf(r, x);
}

__device__ __forceinline__ unsigned short bf16_rtne(float x) {
    unsigned int u = __float_as_uint(x);
    return (unsigned short)((u + 0x7FFFu + ((u >> 16) & 1u)) >> 16);
}
__device__ __forceinline__ void split_bf16(float x, unsigned short& hi, unsigned short& lo) {
    hi = bf16_rtne(x);
    float hf = __uint_as_float(((unsigned int)hi) << 16);
    lo = bf16_rtne(x - hf);
}

__global__ void fillz(float* p, int n) {
    int i = blockIdx.x * blockDim.x + threadIdx.x;
    if (i < n) p[i] = 0.0f;
}

// fp32 [n] -> bf16 hi/lo [n]
__global__ void split_w(const float* __restrict__ W, ushort_t* __restrict__ hi,
                        ushort_t* __restrict__ lo, int n) {
    int i = blockIdx.x * blockDim.x + threadIdx.x;
    if (i < n) {
        unsigned short h, l;
        split_bf16(W[i], h, l);
        hi[i] = h; lo[i] = l;
    }
}

// swizzled 16-byte-slot index for a [R][32 bf16] row-major LDS tile
// (row = 64 B = 4 slots; XOR-ish rotate keeps fragment reads conflict-free)
#define SW16(r, kg) ((((r) << 2) | (((kg) + ((r) >> 1)) & 3)))

// ---------------------------------------------------------------------------
// bf16-split MFMA LSTM step.
// g = init + h @ W_hh^T  via  h_hi*W_hi + h_lo*W_hi + h_hi*W_lo  (3-term
// split precision, fp32 MFMA accumulate; residual ~2^-17 relative).
// grid (8,32): block tile 64 f-rows x (32 cols x 4 gates); wave w = gate w,
// wave tile 64x32 = 4x2 subtiles of mfma_f32_16x16x32_bf16.
// Epilogue: gates exchanged via LDS, fused cell update, writes h as
// fp32 + bf16 hi/lo (so next step's A staging is a pure copy).
// ---------------------------------------------------------------------------
__global__ __launch_bounds__(256) void lstm_step_mfma(
    const float* __restrict__ h_in,      // fp32 [512][1024]
    const ushort_t* __restrict__ hhi,    // bf16 [512][1024]
    const ushort_t* __restrict__ hlo,
    float* __restrict__ h_out,
    ushort_t* __restrict__ hhi_o,
    ushort_t* __restrict__ hlo_o,
    float* __restrict__ c_st,            // fp32 [512][1024]
    const ushort_t* __restrict__ Whi,    // bf16 [4096][1024]
    const ushort_t* __restrict__ Wlo,
    const float* __restrict__ initE,     // embW [128][4096] or u_p [512][4096]
    const int* __restrict__ tokens,      // [512][128] or null
    const int* __restrict__ lengths,     // [512] or null
    int t)
{
    __shared__ __align__(16) char smem[32768];
    char* As_hi = smem;                  // 4 KB: 64 rows x 32 bf16 (swizzled)
    char* As_lo = smem + 4096;
    char* Bs_hi = smem + 8192;           // 8 KB: 128 rows x 32 bf16
    char* Bs_lo = smem + 16384;
    float* Gx = (float*)smem;            // epilogue reuse: [4][64][32] fp32

    const int tid = threadIdx.x;
    const int w = tid >> 6;              // wave index = gate
    const int l = tid & 63;
    const int fbase = blockIdx.x * 64;
    const int n0 = blockIdx.y * 32;

    // --- staging maps ---
    // A: 256 slots of 16 B per array -> 1 slot/thread
    const int ar = tid >> 2;             // 0..63
    const int akg = tid & 3;
    const size_t a_goff = (size_t)(fbase + ar) * HH + akg * 8;
    // B: 512 slots per array -> 2 slots/thread (idx = tid, tid+256)
    const int br0 = tid >> 2;            // 0..63
    const int br1 = (tid + 256) >> 2;    // 64..127
    const int bkg = tid & 3;
    const size_t b_goff0 = ((size_t)(br0 >> 5) * HH + n0 + (br0 & 31)) * HH + bkg * 8;
    const size_t b_goff1 = ((size_t)(br1 >> 5) * HH + n0 + (br1 & 31)) * HH + bkg * 8;

    floatx4 acc[4][2];
    #pragma unroll
    for (int m = 0; m < 4; ++m)
        #pragma unroll
        for (int n = 0; n < 2; ++n) acc[m][n] = (floatx4)(0.0f);

    // prefetch chunk 0
    int4 pa_h = *(const int4*)(hhi + a_goff);
    int4 pa_l = *(const int4*)(hlo + a_goff);
    int4 pb_h0 = *(const int4*)(Whi + b_goff0);
    int4 pb_h1 = *(const int4*)(Whi + b_goff1);
    int4 pb_l0 = *(const int4*)(Wlo + b_goff0);
    int4 pb_l1 = *(const int4*)(Wlo + b_goff1);

    const int q = l >> 4;                // k-group 0..3
    const int fr = l & 15;               // fragment row/col

    for (int kc = 0; kc < 32; ++kc) {
        __syncthreads();
        ((int4*)As_hi)[SW16(ar, akg)] = pa_h;
        ((int4*)As_lo)[SW16(ar, akg)] = pa_l;
        ((int4*)Bs_hi)[SW16(br0, bkg)] = pb_h0;
        ((int4*)Bs_hi)[SW16(br1, bkg)] = pb_h1;
        ((int4*)Bs_lo)[SW16(br0, bkg)] = pb_l0;
        ((int4*)Bs_lo)[SW16(br1, bkg)] = pb_l1;
        __syncthreads();

        if (kc < 31) {
            const int k0 = (kc + 1) * 32;
            pa_h = *(const int4*)(hhi + a_goff + k0);
            pa_l = *(const int4*)(hlo + a_goff + k0);
            pb_h0 = *(const int4*)(Whi + b_goff0 + k0);
            pb_h1 = *(const int4*)(Whi + b_goff1 + k0);
            pb_l0 = *(const int4*)(Wlo + b_goff0 + k0);
            pb_l1 = *(const int4*)(Wlo + b_goff1 + k0);
        }

        short8 a_h[4], a_l[4], b_h[2], b_l[2];
        #pragma unroll
        for (int m = 0; m < 4; ++m) {
            const int r = m * 16 + fr;
            a_h[m] = *(const short8*)(As_hi + SW16(r, q) * 16);
            a_l[m] = *(const short8*)(As_lo + SW16(r, q) * 16);
        }
        #pragma unroll
        for (int n = 0; n < 2; ++n) {
            const int r = w * 32 + n * 16 + fr;
            b_h[n] = *(const short8*)(Bs_hi + SW16(r, q) * 16);
            b_l[n] = *(const short8*)(Bs_lo + SW16(r, q) * 16);
        }

        #pragma unroll
        for (int m = 0; m < 4; ++m)
            #pragma unroll
            for (int n = 0; n < 2; ++n) {
                acc[m][n] = __builtin_amdgcn_mfma_f32_16x16x32_bf16(a_h[m], b_h[n], acc[m][n], 0, 0, 0);
                acc[m][n] = __builtin_amdgcn_mfma_f32_16x16x32_bf16(a_l[m], b_h[n], acc[m][n], 0, 0, 0);
                acc[m][n] = __builtin_amdgcn_mfma_f32_16x16x32_bf16(a_h[m], b_l[n], acc[m][n], 0, 0, 0);
            }
    }

    // --- gate exchange: C/D layout col = l&15, row = (l>>4)*4 + reg ---
    __syncthreads();
    #pragma unroll
    for (int m = 0; m < 4; ++m)
        #pragma unroll
        for (int n = 0; n < 2; ++n)
            #pragma unroll
            for (int r = 0; r < 4; ++r) {
                const int row = m * 16 + q * 4 + r;
                const int col = n * 16 + fr;
                Gx[(w * 64 + row) * 32 + col] = acc[m][n][r];
            }
    __syncthreads();

    // --- fused cell update: thread -> (row = tid>>2, 8 cols) ---
    const int rr = tid >> 2;
    const int c0 = (tid & 3) * 8;
    const int f = fbase + rr;
    const float* ib = tokens ? (initE + (size_t)tokens[f * LL + t] * 4096)
                             : (initE + (size_t)f * 4096);
    const bool upd = lengths ? (t < lengths[f]) : true;

    #pragma unroll
    for (int j = 0; j < 8; ++j) {
        const int c = c0 + j;
        const int gc = n0 + c;
        const size_t gidx = (size_t)f * HH + gc;
        float gi = Gx[(0 * 64 + rr) * 32 + c] + ib[gc];
        float gf = Gx[(1 * 64 + rr) * 32 + c] + ib[1024 + gc];
        float gg = Gx[(2 * 64 + rr) * 32 + c] + ib[2048 + gc];
        float go = Gx[(3 * 64 + rr) * 32 + c] + ib[3072 + gc];

        float cold = c_st[gidx];
        float cn = sigm(gf) * cold + sigm(gi) * tanh_fast(gg);
        float hn = sigm(go) * tanh_fast(cn);
        float hold = h_in[gidx];

        float cw = upd ? cn : cold;
        float hw = upd ? hn : hold;
        c_st[gidx] = cw;
        h_out[gidx] = hw;
        unsigned short hi, lo;
        split_bf16(hw, hi, lo);
        hhi_o[gidx] = hi;
        hlo_o[gidx] = lo;
    }
}

// ---------------------------------------------------------------------------
// Generic fp32 C[M][N] = A[M][K] @ W[N][K]^T + bias[N]
// grid (M/32, N/64), block 256; per thread 4x2.
// ---------------------------------------------------------------------------
__global__ __launch_bounds__(256) void gemm_bias(
    const float* __restrict__ A, const float* __restrict__ W,
    const float* __restrict__ bias, float* __restrict__ C,
    int N, int K)
{
    __shared__ __align__(16) float As[16][32];
    __shared__ __align__(16) float Bs[16][64];
    const int tid = threadIdx.x;
    const int tm = tid & 7;
    const int tn = tid >> 3;
    const int m0 = blockIdx.x * 32, n0 = blockIdx.y * 64;
    const int am = tid >> 3;
    const int ak = (tid & 7) * 2;
    const int br = tid >> 2;
    const int bk = (tid & 3) * 4;
    const float* arow = A + (size_t)(m0 + am) * K;
    const float* brow = W + (size_t)(n0 + br) * K;
    float acc[4][2] = {};
    const int tm4 = tm * 4, tn2 = tn * 2;

    for (int k0 = 0; k0 < K; k0 += 16) {
        __syncthreads();
        float2 av = *(const float2*)(arow + k0 + ak);
        float4 bv = *(const float4*)(brow + k0 + bk);
        As[ak][am] = av.x; As[ak + 1][am] = av.y;
        Bs[bk][br] = bv.x; Bs[bk + 1][br] = bv.y;
        Bs[bk + 2][br] = bv.z; Bs[bk + 3][br] = bv.w;
        __syncthreads();
        #pragma unroll
        for (int k = 0; k < 16; ++k) {
            float4 a = *(const float4*)&As[k][tm4];
            float2 b = *(const float2*)&Bs[k][tn2];
            acc[0][0] += a.x * b.x; acc[0][1] += a.x * b.y;
            acc[1][0] += a.y * b.x; acc[1][1] += a.y * b.y;
            acc[2][0] += a.z * b.x; acc[2][1] += a.z * b.y;
            acc[3][0] += a.w * b.x; acc[3][1] += a.w * b.y;
        }
    }
    float b0 = bias[n0 + tn2], b1 = bias[n0 + tn2 + 1];
    #pragma unroll
    for (int mi = 0; mi < 4; ++mi) {
        float2 o;
        o.x = acc[mi][0] + b0;
        o.y = acc[mi][1] + b1;
        *(float2*)(C + (size_t)(m0 + tm4 + mi) * N + n0 + tn2) = o;
    }
}

// ---------------------------------------------------------------------------
// pooled[b][n] = tanh(max_e (h[4b+e] @ W_mp^T) + b_mp)   (tanh monotone)
// ---------------------------------------------------------------------------
__global__ __launch_bounds__(256) void mp_pool(
    const float* __restrict__ h, const float* __restrict__ Wmp,
    const float* __restrict__ bmp, float* __restrict__ pooled)
{
    __shared__ __align__(16) float As[16][32];
    __shared__ __align__(16) float Bs[16][64];
    const int tid = threadIdx.x;
    const int tm = tid & 7;
    const int tn = tid >> 3;
    const int m0 = blockIdx.x * 32, n0 = blockIdx.y * 64;
    const int am = tid >> 3;
    const int ak = (tid & 7) * 2;
    const int br = tid >> 2;
    const int bk = (tid & 3) * 4;
    const float* arow = h + (size_t)(m0 + am) * HH;
    const float* brow = Wmp + (size_t)(n0 + br) * HH;
    float acc[4][2] = {};
    const int tm4 = tm * 4, tn2 = tn * 2;

    for (int k0 = 0; k0 < HH; k0 += 16) {
        __syncthreads();
        float2 av = *(const float2*)(arow + k0 + ak);
        float4 bv = *(const float4*)(brow + k0 + bk);
        As[ak][am] = av.x; As[ak + 1][am] = av.y;
        Bs[bk][br] = bv.x; Bs[bk + 1][br] = bv.y;
        Bs[bk + 2][br] = bv.z; Bs[bk + 3][br] = bv.w;
        __syncthreads();
        #pragma unroll
        for (int k = 0; k < 16; ++k) {
            float4 a = *(const float4*)&As[k][tm4];
            float2 b = *(const float2*)&Bs[k][tn2];
            acc[0][0] += a.x * b.x; acc[0][1] += a.x * b.y;
            acc[1][0] += a.y * b.x; acc[1][1] += a.y * b.y;
            acc[2][0] += a.z * b.x; acc[2][1] += a.z * b.y;
            acc[3][0] += a.w * b.x; acc[3][1] += a.w * b.y;
        }
    }
    float mx0 = fmaxf(fmaxf(acc[0][0], acc[1][0]), fmaxf(acc[2][0], acc[3][0]));
    float mx1 = fmaxf(fmaxf(acc[0][1], acc[1][1]), fmaxf(acc[2][1], acc[3][1]));
    mx0 += bmp[n0 + tn2];
    mx1 += bmp[n0 + tn2 + 1];
    float2 o;
    o.x = tanh_fast(mx0);
    o.y = tanh_fast(mx1);
    const int bidx = (m0 >> 2) + tm;
    *(float2*)(pooled + (size_t)bidx * HH + n0 + tn2) = o;
}

extern "C" void kernel_launch(void* const* d_in, const int* in_sizes, int n_in,
                              void* d_out, int out_size, void* d_ws, size_t ws_size,
                              hipStream_t stream)
{
    const int*   tokens_in   = (const int*)d_in[0];
    const int*   lengths_in  = (const int*)d_in[1];
    const int*   tokens_out  = (const int*)d_in[2];
    const int*   lengths_out = (const int*)d_in[3];
    const float* embedding   = (const float*)d_in[4];
    const float* W_ih_in     = (const float*)d_in[5];
    const float* W_hh_in     = (const float*)d_in[6];
    const float* b_in        = (const float*)d_in[7];
    const float* W_ih_out    = (const float*)d_in[8];
    const float* W_hh_out    = (const float*)d_in[9];
    const float* b_out       = (const float*)d_in[10];
    const float* W_ih_p      = (const float*)d_in[11];
    const float* W_hh_p      = (const float*)d_in[12];
    const float* b_p         = (const float*)d_in[13];
    const float* W_mp        = (const float*)d_in[14];
    const float* b_mp        = (const float*)d_in[15];
    const float* W_sm        = (const float*)d_in[16];
    const float* b_sm        = (const float*)d_in[17];
    float* out = (float*)d_out;

    // workspace layout (float units); total ~18.5M floats = 74 MB
    float* ws = (float*)d_ws;
    float* h_a      = ws;                  // 524288
    float* h_b      = ws + 524288;         // 524288
    float* c_st     = ws + 1048576;        // 524288
    float* embW_in  = ws + 1572864;        // 524288
    float* embW_out = ws + 2097152;        // 524288
    float* u_p      = ws + 2621440;        // 2097152
    float* pooled   = ws + 4718592;        // 131072
    ushort_t* hhi_a = (ushort_t*)(ws + 4849664);   // 524288 bf16
    ushort_t* hlo_a = (ushort_t*)(ws + 5111808);
    ushort_t* hhi_b = (ushort_t*)(ws + 5373952);
    ushort_t* hlo_b = (ushort_t*)(ws + 5636096);
    ushort_t* Whi_in  = (ushort_t*)(ws + 5898240); // 4194304 bf16 each
    ushort_t* Wlo_in  = (ushort_t*)(ws + 7995392);
    ushort_t* Whi_out = (ushort_t*)(ws + 10092544);
    ushort_t* Wlo_out = (ushort_t*)(ws + 12189696);
    ushort_t* Whi_p   = (ushort_t*)(ws + 14286848);
    ushort_t* Wlo_p   = (ushort_t*)(ws + 16384000);

    // zero h0, c0, and h0's bf16 hi/lo (hhi_a/hlo_a are adjacent)
    fillz<<<2048, 256, 0, stream>>>(h_a, 524288);
    fillz<<<2048, 256, 0, stream>>>(c_st, 524288);
    fillz<<<2048, 256, 0, stream>>>(ws + 4849664, 524288);

    // split the three recurrent weight matrices into bf16 hi/lo
    split_w<<<16384, 256, 0, stream>>>(W_hh_in,  Whi_in,  Wlo_in,  4194304);
    split_w<<<16384, 256, 0, stream>>>(W_hh_out, Whi_out, Wlo_out, 4194304);
    split_w<<<16384, 256, 0, stream>>>(W_hh_p,   Whi_p,   Wlo_p,   4194304);

    // embW = embedding @ W_ih^T + b  (x @ W_ih collapses to a gather)
    gemm_bias<<<dim3(4, 64), 256, 0, stream>>>(embedding, W_ih_in, b_in, embW_in, 4096, 128);
    gemm_bias<<<dim3(4, 64), 256, 0, stream>>>(embedding, W_ih_out, b_out, embW_out, 4096, 128);

    float* hc = h_a;  ushort_t* hic = hhi_a;  ushort_t* loc = hlo_a;
    float* hn = h_b;  ushort_t* hin = hhi_b;  ushort_t* lon = hlo_b;

    for (int t = 0; t < 128; ++t) {
        lstm_step_mfma<<<dim3(8, 32), 256, 0, stream>>>(
            hc, hic, loc, hn, hin, lon, c_st, Whi_in, Wlo_in, embW_in,
            tokens_in, lengths_in, t);
        float* tf = hc; hc = hn; hn = tf;
        ushort_t* th = hic; hic = hin; hin = th;
        ushort_t* tl = loc; loc = lon; lon = tl;
    }
    for (int t = 0; t < 128; ++t) {
        lstm_step_mfma<<<dim3(8, 32), 256, 0, stream>>>(
            hc, hic, loc, hn, hin, lon, c_st, Whi_out, Wlo_out, embW_out,
            tokens_out, lengths_out, t);
        float* tf = hc; hc = hn; hn = tf;
        ushort_t* th = hic; hic = hin; hin = th;
        ushort_t* tl = loc; loc = lon; lon = tl;
    }

    // u_p = prev_h @ W_ih_p^T + b_p  (prev_h constant across all 16 steps)
    gemm_bias<<<dim3(16, 64), 256, 0, stream>>>(hc, W_ih_p, b_p, u_p, 4096, 1024);

    for (int t = 0; t < 16; ++t) {
        lstm_step_mfma<<<dim3(8, 32), 256, 0, stream>>>(
            hc, hic, loc, hn, hin, lon, c_st, Whi_p, Wlo_p, u_p,
            nullptr, nullptr, t);
        mp_pool<<<dim3(16, 16), 256, 0, stream>>>(hn, W_mp, b_mp, pooled);
        gemm_bias<<<dim3(4, 16), 256, 0, stream>>>(pooled, W_sm, b_sm,
                                                   out + (size_t)t * (BB * PP), 1024, 1024);
        float* tf = hc; hc = hn; hn = tf;
        ushort_t* th = hic; hic = hin; hin = th;
        ushort_t* tl = loc; loc = lon; lon = tl;
    }
}

// Round 3
// 10007.069 us; speedup vs baseline: 2.7038x; 1.1200x over previous
//
#include <hip/hip_runtime.h>

#define FF 512
#define HH 1024
#define LL 128
#define BB 128
#define PP 1024

typedef short short8 __attribute__((ext_vector_type(8)));
typedef float floatx4 __attribute__((ext_vector_type(4)));
typedef unsigned short ushort_t;

__device__ __forceinline__ float sigm(float x) {
    return 1.0f / (1.0f + __expf(-x));
}
// overflow-safe tanh: exp(-2|x|) underflows to 0 for large |x| -> +-1
__device__ __forceinline__ float tanh_fast(float x) {
    float ax = fabsf(x);
    float e = __expf(-2.0f * ax);
    float r = (1.0f - e) / (1.0f + e);
    return copysignf(r, x);
}

__device__ __forceinline__ unsigned short bf16_rtne(float x) {
    unsigned int u = __float_as_uint(x);
    return (unsigned short)((u + 0x7FFFu + ((u >> 16) & 1u)) >> 16);
}
__device__ __forceinline__ void split_bf16(float x, unsigned short& hi, unsigned short& lo) {
    hi = bf16_rtne(x);
    float hf = __uint_as_float(((unsigned int)hi) << 16);
    lo = bf16_rtne(x - hf);
}

__global__ void fillz(float* p, int n) {
    int i = blockIdx.x * blockDim.x + threadIdx.x;
    if (i < n) p[i] = 0.0f;
}

// fp32 [n] -> bf16 hi/lo [n]
__global__ void split_w(const float* __restrict__ W, ushort_t* __restrict__ hi,
                        ushort_t* __restrict__ lo, int n) {
    int i = blockIdx.x * blockDim.x + threadIdx.x;
    if (i < n) {
        unsigned short h, l;
        split_bf16(W[i], h, l);
        hi[i] = h; lo[i] = l;
    }
}

// swizzled 16-byte-slot index for a [R][32 bf16] row-major LDS tile
// (row = 64 B = 4 slots; rotate keeps fragment reads conflict-free)
#define SW16(r, kg) ((((r) << 2) | (((kg) + ((r) >> 1)) & 3)))

// ---------------------------------------------------------------------------
// bf16-split MFMA LSTM step.
// g = init + h @ W_hh^T  via  h_hi*W_hi + h_lo*W_hi + h_hi*W_lo.
// 1D grid of 256 blocks, XCD-swizzled: all 8 f-tiles (bx) of one n-slice (by)
// land on the SAME XCD (id%8 round-robin), so each XCD's 2 MB W-slice stays
// L2-resident across all 128 timesteps (L2 persists across launches and the
// id->XCD map is deterministic).
// Block tile: 64 f-rows x (32 cols x 4 gates); wave = gate; 4x2 subtiles of
// mfma_f32_16x16x32_bf16. Epilogue: LDS gate exchange + fused cell update,
// h written as fp32 + bf16 hi/lo so next step's A staging is a pure copy.
// ---------------------------------------------------------------------------
__global__ __launch_bounds__(256) void lstm_step_mfma(
    const float* __restrict__ h_in,      // fp32 [512][1024]
    const ushort_t* __restrict__ hhi,    // bf16 [512][1024]
    const ushort_t* __restrict__ hlo,
    float* __restrict__ h_out,
    ushort_t* __restrict__ hhi_o,
    ushort_t* __restrict__ hlo_o,
    float* __restrict__ c_st,            // fp32 [512][1024]
    const ushort_t* __restrict__ Whi,    // bf16 [4096][1024]
    const ushort_t* __restrict__ Wlo,
    const float* __restrict__ initE,     // embW [128][4096] or u_p [512][4096]
    const int* __restrict__ tokens,      // [512][128] or null
    const int* __restrict__ lengths,     // [512] or null
    int t)
{
    __shared__ __align__(16) char smem[32768];
    char* As_hi = smem;                  // 4 KB: 64 rows x 32 bf16 (swizzled)
    char* As_lo = smem + 4096;
    char* Bs_hi = smem + 8192;           // 8 KB: 128 rows x 32 bf16
    char* Bs_lo = smem + 16384;
    float* Gx = (float*)smem;            // epilogue reuse: [4][64][32] fp32

    const int tid = threadIdx.x;
    const int w = tid >> 6;              // wave index = gate
    const int l = tid & 63;

    // XCD-aware decode: xcd = id&7; by in {xcd, xcd+8, xcd+16, xcd+24}
    const int id = blockIdx.x;
    const int by = (id & 7) + 8 * ((id >> 3) & 3);
    const int bx = id >> 5;
    const int fbase = bx * 64;
    const int n0 = by * 32;

    // --- staging maps ---
    const int ar = tid >> 2;             // 0..63
    const int akg = tid & 3;
    const size_t a_goff = (size_t)(fbase + ar) * HH + akg * 8;
    const int br0 = tid >> 2;            // 0..63
    const int br1 = (tid + 256) >> 2;    // 64..127
    const int bkg = tid & 3;
    const size_t b_goff0 = ((size_t)(br0 >> 5) * HH + n0 + (br0 & 31)) * HH + bkg * 8;
    const size_t b_goff1 = ((size_t)(br1 >> 5) * HH + n0 + (br1 & 31)) * HH + bkg * 8;

    floatx4 acc[4][2];
    #pragma unroll
    for (int m = 0; m < 4; ++m)
        #pragma unroll
        for (int n = 0; n < 2; ++n) acc[m][n] = (floatx4)(0.0f);

    // prefetch chunk 0
    int4 pa_h = *(const int4*)(hhi + a_goff);
    int4 pa_l = *(const int4*)(hlo + a_goff);
    int4 pb_h0 = *(const int4*)(Whi + b_goff0);
    int4 pb_h1 = *(const int4*)(Whi + b_goff1);
    int4 pb_l0 = *(const int4*)(Wlo + b_goff0);
    int4 pb_l1 = *(const int4*)(Wlo + b_goff1);

    const int q = l >> 4;                // k-group 0..3
    const int fr = l & 15;               // fragment row/col

    for (int kc = 0; kc < 32; ++kc) {
        __syncthreads();
        ((int4*)As_hi)[SW16(ar, akg)] = pa_h;
        ((int4*)As_lo)[SW16(ar, akg)] = pa_l;
        ((int4*)Bs_hi)[SW16(br0, bkg)] = pb_h0;
        ((int4*)Bs_hi)[SW16(br1, bkg)] = pb_h1;
        ((int4*)Bs_lo)[SW16(br0, bkg)] = pb_l0;
        ((int4*)Bs_lo)[SW16(br1, bkg)] = pb_l1;
        __syncthreads();

        if (kc < 31) {
            const int k0 = (kc + 1) * 32;
            pa_h = *(const int4*)(hhi + a_goff + k0);
            pa_l = *(const int4*)(hlo + a_goff + k0);
            pb_h0 = *(const int4*)(Whi + b_goff0 + k0);
            pb_h1 = *(const int4*)(Whi + b_goff1 + k0);
            pb_l0 = *(const int4*)(Wlo + b_goff0 + k0);
            pb_l1 = *(const int4*)(Wlo + b_goff1 + k0);
        }

        short8 a_h[4], a_l[4], b_h[2], b_l[2];
        #pragma unroll
        for (int m = 0; m < 4; ++m) {
            const int r = m * 16 + fr;
            a_h[m] = *(const short8*)(As_hi + SW16(r, q) * 16);
            a_l[m] = *(const short8*)(As_lo + SW16(r, q) * 16);
        }
        #pragma unroll
        for (int n = 0; n < 2; ++n) {
            const int r = w * 32 + n * 16 + fr;
            b_h[n] = *(const short8*)(Bs_hi + SW16(r, q) * 16);
            b_l[n] = *(const short8*)(Bs_lo + SW16(r, q) * 16);
        }

        #pragma unroll
        for (int m = 0; m < 4; ++m)
            #pragma unroll
            for (int n = 0; n < 2; ++n) {
                acc[m][n] = __builtin_amdgcn_mfma_f32_16x16x32_bf16(a_h[m], b_h[n], acc[m][n], 0, 0, 0);
                acc[m][n] = __builtin_amdgcn_mfma_f32_16x16x32_bf16(a_l[m], b_h[n], acc[m][n], 0, 0, 0);
                acc[m][n] = __builtin_amdgcn_mfma_f32_16x16x32_bf16(a_h[m], b_l[n], acc[m][n], 0, 0, 0);
            }
    }

    // --- gate exchange: C/D layout col = l&15, row = (l>>4)*4 + reg ---
    __syncthreads();
    #pragma unroll
    for (int m = 0; m < 4; ++m)
        #pragma unroll
        for (int n = 0; n < 2; ++n)
            #pragma unroll
            for (int r = 0; r < 4; ++r) {
                const int row = m * 16 + q * 4 + r;
                const int col = n * 16 + fr;
                Gx[(w * 64 + row) * 32 + col] = acc[m][n][r];
            }
    __syncthreads();

    // --- fused cell update: thread -> (row = tid>>2, 8 cols) ---
    const int rr = tid >> 2;
    const int c0 = (tid & 3) * 8;
    const int f = fbase + rr;
    const float* ib = tokens ? (initE + (size_t)tokens[f * LL + t] * 4096)
                             : (initE + (size_t)f * 4096);
    const bool upd = lengths ? (t < lengths[f]) : true;

    #pragma unroll
    for (int j = 0; j < 8; ++j) {
        const int c = c0 + j;
        const int gc = n0 + c;
        const size_t gidx = (size_t)f * HH + gc;
        float gi = Gx[(0 * 64 + rr) * 32 + c] + ib[gc];
        float gf = Gx[(1 * 64 + rr) * 32 + c] + ib[1024 + gc];
        float gg = Gx[(2 * 64 + rr) * 32 + c] + ib[2048 + gc];
        float go = Gx[(3 * 64 + rr) * 32 + c] + ib[3072 + gc];

        float cold = c_st[gidx];
        float cn = sigm(gf) * cold + sigm(gi) * tanh_fast(gg);
        float hn = sigm(go) * tanh_fast(cn);
        float hold = h_in[gidx];

        float cw = upd ? cn : cold;
        float hw = upd ? hn : hold;
        c_st[gidx] = cw;
        h_out[gidx] = hw;
        unsigned short hi, lo;
        split_bf16(hw, hi, lo);
        hhi_o[gidx] = hi;
        hlo_o[gidx] = lo;
    }
}

// ---------------------------------------------------------------------------
// Generic fp32 C[M][N] = A[M][K] @ W[N][K]^T + bias[N]
// grid (M/32, N/64), block 256; per thread 4x2.
// ---------------------------------------------------------------------------
__global__ __launch_bounds__(256) void gemm_bias(
    const float* __restrict__ A, const float* __restrict__ W,
    const float* __restrict__ bias, float* __restrict__ C,
    int N, int K)
{
    __shared__ __align__(16) float As[16][32];
    __shared__ __align__(16) float Bs[16][64];
    const int tid = threadIdx.x;
    const int tm = tid & 7;
    const int tn = tid >> 3;
    const int m0 = blockIdx.x * 32, n0 = blockIdx.y * 64;
    const int am = tid >> 3;
    const int ak = (tid & 7) * 2;
    const int br = tid >> 2;
    const int bk = (tid & 3) * 4;
    const float* arow = A + (size_t)(m0 + am) * K;
    const float* brow = W + (size_t)(n0 + br) * K;
    float acc[4][2] = {};
    const int tm4 = tm * 4, tn2 = tn * 2;

    for (int k0 = 0; k0 < K; k0 += 16) {
        __syncthreads();
        float2 av = *(const float2*)(arow + k0 + ak);
        float4 bv = *(const float4*)(brow + k0 + bk);
        As[ak][am] = av.x; As[ak + 1][am] = av.y;
        Bs[bk][br] = bv.x; Bs[bk + 1][br] = bv.y;
        Bs[bk + 2][br] = bv.z; Bs[bk + 3][br] = bv.w;
        __syncthreads();
        #pragma unroll
        for (int k = 0; k < 16; ++k) {
            float4 a = *(const float4*)&As[k][tm4];
            float2 b = *(const float2*)&Bs[k][tn2];
            acc[0][0] += a.x * b.x; acc[0][1] += a.x * b.y;
            acc[1][0] += a.y * b.x; acc[1][1] += a.y * b.y;
            acc[2][0] += a.z * b.x; acc[2][1] += a.z * b.y;
            acc[3][0] += a.w * b.x; acc[3][1] += a.w * b.y;
        }
    }
    float b0 = bias[n0 + tn2], b1 = bias[n0 + tn2 + 1];
    #pragma unroll
    for (int mi = 0; mi < 4; ++mi) {
        float2 o;
        o.x = acc[mi][0] + b0;
        o.y = acc[mi][1] + b1;
        *(float2*)(C + (size_t)(m0 + tm4 + mi) * N + n0 + tn2) = o;
    }
}

// ---------------------------------------------------------------------------
// pooled[b][n] = tanh(max_e (h[4b+e] @ W_mp^T) + b_mp)   (tanh monotone)
// ---------------------------------------------------------------------------
__global__ __launch_bounds__(256) void mp_pool(
    const float* __restrict__ h, const float* __restrict__ Wmp,
    const float* __restrict__ bmp, float* __restrict__ pooled)
{
    __shared__ __align__(16) float As[16][32];
    __shared__ __align__(16) float Bs[16][64];
    const int tid = threadIdx.x;
    const int tm = tid & 7;
    const int tn = tid >> 3;
    const int m0 = blockIdx.x * 32, n0 = blockIdx.y * 64;
    const int am = tid >> 3;
    const int ak = (tid & 7) * 2;
    const int br = tid >> 2;
    const int bk = (tid & 3) * 4;
    const float* arow = h + (size_t)(m0 + am) * HH;
    const float* brow = Wmp + (size_t)(n0 + br) * HH;
    float acc[4][2] = {};
    const int tm4 = tm * 4, tn2 = tn * 2;

    for (int k0 = 0; k0 < HH; k0 += 16) {
        __syncthreads();
        float2 av = *(const float2*)(arow + k0 + ak);
        float4 bv = *(const float4*)(brow + k0 + bk);
        As[ak][am] = av.x; As[ak + 1][am] = av.y;
        Bs[bk][br] = bv.x; Bs[bk + 1][br] = bv.y;
        Bs[bk + 2][br] = bv.z; Bs[bk + 3][br] = bv.w;
        __syncthreads();
        #pragma unroll
        for (int k = 0; k < 16; ++k) {
            float4 a = *(const float4*)&As[k][tm4];
            float2 b = *(const float2*)&Bs[k][tn2];
            acc[0][0] += a.x * b.x; acc[0][1] += a.x * b.y;
            acc[1][0] += a.y * b.x; acc[1][1] += a.y * b.y;
            acc[2][0] += a.z * b.x; acc[2][1] += a.z * b.y;
            acc[3][0] += a.w * b.x; acc[3][1] += a.w * b.y;
        }
    }
    float mx0 = fmaxf(fmaxf(acc[0][0], acc[1][0]), fmaxf(acc[2][0], acc[3][0]));
    float mx1 = fmaxf(fmaxf(acc[0][1], acc[1][1]), fmaxf(acc[2][1], acc[3][1]));
    mx0 += bmp[n0 + tn2];
    mx1 += bmp[n0 + tn2 + 1];
    float2 o;
    o.x = tanh_fast(mx0);
    o.y = tanh_fast(mx1);
    const int bidx = (m0 >> 2) + tm;
    *(float2*)(pooled + (size_t)bidx * HH + n0 + tn2) = o;
}

extern "C" void kernel_launch(void* const* d_in, const int* in_sizes, int n_in,
                              void* d_out, int out_size, void* d_ws, size_t ws_size,
                              hipStream_t stream)
{
    const int*   tokens_in   = (const int*)d_in[0];
    const int*   lengths_in  = (const int*)d_in[1];
    const int*   tokens_out  = (const int*)d_in[2];
    const int*   lengths_out = (const int*)d_in[3];
    const float* embedding   = (const float*)d_in[4];
    const float* W_ih_in     = (const float*)d_in[5];
    const float* W_hh_in     = (const float*)d_in[6];
    const float* b_in        = (const float*)d_in[7];
    const float* W_ih_out    = (const float*)d_in[8];
    const float* W_hh_out    = (const float*)d_in[9];
    const float* b_out       = (const float*)d_in[10];
    const float* W_ih_p      = (const float*)d_in[11];
    const float* W_hh_p      = (const float*)d_in[12];
    const float* b_p         = (const float*)d_in[13];
    const float* W_mp        = (const float*)d_in[14];
    const float* b_mp        = (const float*)d_in[15];
    const float* W_sm        = (const float*)d_in[16];
    const float* b_sm        = (const float*)d_in[17];
    float* out = (float*)d_out;

    // workspace layout (float units); total ~18.5M floats = 74 MB
    float* ws = (float*)d_ws;
    float* h_a      = ws;                  // 524288
    float* h_b      = ws + 524288;         // 524288
    float* c_st     = ws + 1048576;        // 524288
    float* embW_in  = ws + 1572864;        // 524288
    float* embW_out = ws + 2097152;        // 524288
    float* u_p      = ws + 2621440;        // 2097152
    float* pooled   = ws + 4718592;        // 131072
    ushort_t* hhi_a = (ushort_t*)(ws + 4849664);   // 524288 bf16
    ushort_t* hlo_a = (ushort_t*)(ws + 5111808);
    ushort_t* hhi_b = (ushort_t*)(ws + 5373952);
    ushort_t* hlo_b = (ushort_t*)(ws + 5636096);
    ushort_t* Whi_in  = (ushort_t*)(ws + 5898240); // 4194304 bf16 each
    ushort_t* Wlo_in  = (ushort_t*)(ws + 7995392);
    ushort_t* Whi_out = (ushort_t*)(ws + 10092544);
    ushort_t* Wlo_out = (ushort_t*)(ws + 12189696);
    ushort_t* Whi_p   = (ushort_t*)(ws + 14286848);
    ushort_t* Wlo_p   = (ushort_t*)(ws + 16384000);

    // zero h0, c0, and h0's bf16 hi/lo (hhi_a/hlo_a are adjacent)
    fillz<<<2048, 256, 0, stream>>>(h_a, 524288);
    fillz<<<2048, 256, 0, stream>>>(c_st, 524288);
    fillz<<<2048, 256, 0, stream>>>(ws + 4849664, 524288);

    // split the three recurrent weight matrices into bf16 hi/lo
    split_w<<<16384, 256, 0, stream>>>(W_hh_in,  Whi_in,  Wlo_in,  4194304);
    split_w<<<16384, 256, 0, stream>>>(W_hh_out, Whi_out, Wlo_out, 4194304);
    split_w<<<16384, 256, 0, stream>>>(W_hh_p,   Whi_p,   Wlo_p,   4194304);

    // embW = embedding @ W_ih^T + b  (x @ W_ih collapses to a gather)
    gemm_bias<<<dim3(4, 64), 256, 0, stream>>>(embedding, W_ih_in, b_in, embW_in, 4096, 128);
    gemm_bias<<<dim3(4, 64), 256, 0, stream>>>(embedding, W_ih_out, b_out, embW_out, 4096, 128);

    float* hc = h_a;  ushort_t* hic = hhi_a;  ushort_t* loc = hlo_a;
    float* hn = h_b;  ushort_t* hin = hhi_b;  ushort_t* lon = hlo_b;

    for (int t = 0; t < 128; ++t) {
        lstm_step_mfma<<<256, 256, 0, stream>>>(
            hc, hic, loc, hn, hin, lon, c_st, Whi_in, Wlo_in, embW_in,
            tokens_in, lengths_in, t);
        float* tf = hc; hc = hn; hn = tf;
        ushort_t* th = hic; hic = hin; hin = th;
        ushort_t* tl = loc; loc = lon; lon = tl;
    }
    for (int t = 0; t < 128; ++t) {
        lstm_step_mfma<<<256, 256, 0, stream>>>(
            hc, hic, loc, hn, hin, lon, c_st, Whi_out, Wlo_out, embW_out,
            tokens_out, lengths_out, t);
        float* tf = hc; hc = hn; hn = tf;
        ushort_t* th = hic; hic = hin; hin = th;
        ushort_t* tl = loc; loc = lon; lon = tl;
    }

    // u_p = prev_h @ W_ih_p^T + b_p  (prev_h constant across all 16 steps)
    gemm_bias<<<dim3(16, 64), 256, 0, stream>>>(hc, W_ih_p, b_p, u_p, 4096, 1024);

    for (int t = 0; t < 16; ++t) {
        lstm_step_mfma<<<256, 256, 0, stream>>>(
            hc, hic, loc, hn, hin, lon, c_st, Whi_p, Wlo_p, u_p,
            nullptr, nullptr, t);
        mp_pool<<<dim3(16, 16), 256, 0, stream>>>(hn, W_mp, b_mp, pooled);
        gemm_bias<<<dim3(4, 16), 256, 0, stream>>>(pooled, W_sm, b_sm,
                                                   out + (size_t)t * (BB * PP), 1024, 1024);
        float* tf = hc; hc = hn; hn = tf;
        ushort_t* th = hic; hic = hin; hin = th;
        ushort_t* tl = loc; loc = lon; lon = tl;
    }
}

// Round 4
// 9954.599 us; speedup vs baseline: 2.7181x; 1.0053x over previous
//
#include <hip/hip_runtime.h>

#define FF 512
#define HH 1024
#define LL 128
#define BB 128
#define PP 1024

typedef short short8 __attribute__((ext_vector_type(8)));
typedef float floatx4 __attribute__((ext_vector_type(4)));
typedef unsigned short ushort_t;

__device__ __forceinline__ float sigm(float x) {
    return 1.0f / (1.0f + __expf(-x));
}
// overflow-safe tanh: exp(-2|x|) underflows to 0 for large |x| -> +-1
__device__ __forceinline__ float tanh_fast(float x) {
    float ax = fabsf(x);
    float e = __expf(-2.0f * ax);
    float r = (1.0f - e) / (1.0f + e);
    return copysignf(r, x);
}

__device__ __forceinline__ unsigned short bf16_rtne(float x) {
    unsigned int u = __float_as_uint(x);
    return (unsigned short)((u + 0x7FFFu + ((u >> 16) & 1u)) >> 16);
}
__device__ __forceinline__ void split_bf16(float x, unsigned short& hi, unsigned short& lo) {
    hi = bf16_rtne(x);
    float hf = __uint_as_float(((unsigned int)hi) << 16);
    lo = bf16_rtne(x - hf);
}

__global__ void fillz(float* p, int n) {
    int i = blockIdx.x * blockDim.x + threadIdx.x;
    if (i < n) p[i] = 0.0f;
}

// fp32 [n] -> bf16 hi/lo [n]
__global__ void split_w(const float* __restrict__ W, ushort_t* __restrict__ hi,
                        ushort_t* __restrict__ lo, int n) {
    int i = blockIdx.x * blockDim.x + threadIdx.x;
    if (i < n) {
        unsigned short h, l;
        split_bf16(W[i], h, l);
        hi[i] = h; lo[i] = l;
    }
}

// ---------------------------------------------------------------------------
// bf16-split MFMA LSTM step, v2 (barrier-light):
//   g = init + h @ W_hh^T  via  h_hi*W_hi + h_lo*W_hi + h_hi*W_lo.
// - B (W rows) loaded DIRECT global->fragment registers (no LDS round-trip;
//   same 64B-per-row coalescing as staging), double-buffered across chunks.
// - Only A (shared by all 4 waves) goes through LDS; BK=64, rotate swizzle
//   (slot+row)&7 -> conflict-free fragment reads.
// - 1D grid 256, XCD swizzle keeps each XCD's 2 MB W slice L2-resident.
// Block tile 64f x (32c x 4 gates); wave = gate; 4x2 subtiles 16x16x32.
// ---------------------------------------------------------------------------
__global__ __launch_bounds__(256, 1) void lstm_step_mfma(
    const float* __restrict__ h_in,      // fp32 [512][1024]
    const ushort_t* __restrict__ hhi,    // bf16 [512][1024]
    const ushort_t* __restrict__ hlo,
    float* __restrict__ h_out,
    ushort_t* __restrict__ hhi_o,
    ushort_t* __restrict__ hlo_o,
    float* __restrict__ c_st,            // fp32 [512][1024]
    const ushort_t* __restrict__ Whi,    // bf16 [4096][1024]
    const ushort_t* __restrict__ Wlo,
    const float* __restrict__ initE,     // embW [128][4096] or u_p [512][4096]
    const int* __restrict__ tokens,      // [512][128] or null
    const int* __restrict__ lengths,     // [512] or null
    int t)
{
    __shared__ __align__(16) char smem[36864];
    char* As_hi = smem;                  // 8 KB: 64 rows x 8 slots x 16 B
    char* As_lo = smem + 8192;
    float* Gx = (float*)smem;            // epilogue reuse: [4][64][36] fp32

    const int tid = threadIdx.x;
    const int w = tid >> 6;              // wave index = gate
    const int l = tid & 63;
    const int q = l >> 4;                // k-quad 0..3
    const int fr = l & 15;               // fragment row/col

    // XCD-aware decode: xcd = id&7; by in {xcd, xcd+8, xcd+16, xcd+24}
    const int id = blockIdx.x;
    const int by = (id & 7) + 8 * ((id >> 3) & 3);
    const int bx = id >> 5;
    const int fbase = bx * 64;
    const int n0 = by * 32;

    // --- A staging map: thread -> row ar, logical slots s0=tid&3, s0+4 ---
    const int ar = tid >> 2;
    const int s0 = tid & 3;
    const size_t a_goff = (size_t)(fbase + ar) * HH + s0 * 8;   // +32 for s0+4

    // --- B direct-fragment bases: wave w, subtile n, lane (fr,q) ---
    const size_t brow0 = ((size_t)(w * HH) + n0 + 0 * 16 + fr) * HH + q * 8;
    const size_t brow1 = ((size_t)(w * HH) + n0 + 1 * 16 + fr) * HH + q * 8;

    floatx4 acc[4][2];
    #pragma unroll
    for (int m = 0; m < 4; ++m)
        #pragma unroll
        for (int n = 0; n < 2; ++n) acc[m][n] = (floatx4)(0.0f);

    // prefetch A chunk 0 (2 slots x hi/lo)
    int4 pa_h0 = *(const int4*)(hhi + a_goff);
    int4 pa_h1 = *(const int4*)(hhi + a_goff + 32);
    int4 pa_l0 = *(const int4*)(hlo + a_goff);
    int4 pa_l1 = *(const int4*)(hlo + a_goff + 32);

    // B double buffer: [buf][n][kk]
    short8 Bh[2][2][2], Bl[2][2][2];
    #pragma unroll
    for (int kk = 0; kk < 2; ++kk) {
        Bh[0][0][kk] = *(const short8*)(Whi + brow0 + kk * 32);
        Bh[0][1][kk] = *(const short8*)(Whi + brow1 + kk * 32);
        Bl[0][0][kk] = *(const short8*)(Wlo + brow0 + kk * 32);
        Bl[0][1][kk] = *(const short8*)(Wlo + brow1 + kk * 32);
    }

    const int sw0 = (s0 + ar) & 7;            // swizzled slot for s0
    const int sw1 = ((s0 + 4) + ar) & 7;      // swizzled slot for s0+4

    #pragma unroll 2
    for (int kc = 0; kc < 16; ++kc) {
        const int cur = kc & 1, nxt = cur ^ 1;
        __syncthreads();
        ((int4*)As_hi)[ar * 8 + sw0] = pa_h0;
        ((int4*)As_hi)[ar * 8 + sw1] = pa_h1;
        ((int4*)As_lo)[ar * 8 + sw0] = pa_l0;
        ((int4*)As_lo)[ar * 8 + sw1] = pa_l1;
        __syncthreads();

        if (kc < 15) {
            const int k0 = (kc + 1) * 64;
            pa_h0 = *(const int4*)(hhi + a_goff + k0);
            pa_h1 = *(const int4*)(hhi + a_goff + k0 + 32);
            pa_l0 = *(const int4*)(hlo + a_goff + k0);
            pa_l1 = *(const int4*)(hlo + a_goff + k0 + 32);
            #pragma unroll
            for (int kk = 0; kk < 2; ++kk) {
                Bh[nxt][0][kk] = *(const short8*)(Whi + brow0 + k0 + kk * 32);
                Bh[nxt][1][kk] = *(const short8*)(Whi + brow1 + k0 + kk * 32);
                Bl[nxt][0][kk] = *(const short8*)(Wlo + brow0 + k0 + kk * 32);
                Bl[nxt][1][kk] = *(const short8*)(Wlo + brow1 + k0 + kk * 32);
            }
        }

        #pragma unroll
        for (int m = 0; m < 4; ++m) {
            const int r = m * 16 + fr;
            short8 ah0 = *(const short8*)(As_hi + (r * 8 + ((0 * 4 + q + r) & 7)) * 16);
            short8 ah1 = *(const short8*)(As_hi + (r * 8 + ((1 * 4 + q + r) & 7)) * 16);
            short8 al0 = *(const short8*)(As_lo + (r * 8 + ((0 * 4 + q + r) & 7)) * 16);
            short8 al1 = *(const short8*)(As_lo + (r * 8 + ((1 * 4 + q + r) & 7)) * 16);
            #pragma unroll
            for (int n = 0; n < 2; ++n) {
                acc[m][n] = __builtin_amdgcn_mfma_f32_16x16x32_bf16(ah0, Bh[cur][n][0], acc[m][n], 0, 0, 0);
                acc[m][n] = __builtin_amdgcn_mfma_f32_16x16x32_bf16(al0, Bh[cur][n][0], acc[m][n], 0, 0, 0);
                acc[m][n] = __builtin_amdgcn_mfma_f32_16x16x32_bf16(ah0, Bl[cur][n][0], acc[m][n], 0, 0, 0);
                acc[m][n] = __builtin_amdgcn_mfma_f32_16x16x32_bf16(ah1, Bh[cur][n][1], acc[m][n], 0, 0, 0);
                acc[m][n] = __builtin_amdgcn_mfma_f32_16x16x32_bf16(al1, Bh[cur][n][1], acc[m][n], 0, 0, 0);
                acc[m][n] = __builtin_amdgcn_mfma_f32_16x16x32_bf16(ah1, Bl[cur][n][1], acc[m][n], 0, 0, 0);
            }
        }
    }

    // --- gate exchange (C/D layout: col = fr, row = q*4 + reg); stride 36 ---
    __syncthreads();
    #pragma unroll
    for (int m = 0; m < 4; ++m)
        #pragma unroll
        for (int n = 0; n < 2; ++n)
            #pragma unroll
            for (int r = 0; r < 4; ++r)
                Gx[(w * 64 + m * 16 + q * 4 + r) * 36 + n * 16 + fr] = acc[m][n][r];
    __syncthreads();

    // --- fused cell update: thread -> (row rr, 8 consecutive cols) ---
    const int rr = tid >> 2;
    const int c0 = (tid & 3) * 8;
    const int f = fbase + rr;
    const int gc = n0 + c0;
    const size_t gidx = (size_t)f * HH + gc;
    const float* ib = tokens ? (initE + (size_t)tokens[f * LL + t] * 4096)
                             : (initE + (size_t)f * 4096);
    const bool upd = lengths ? (t < lengths[f]) : true;

    float4 gv[4][2];
    #pragma unroll
    for (int g = 0; g < 4; ++g) {
        gv[g][0] = *(const float4*)&Gx[(g * 64 + rr) * 36 + c0];
        gv[g][1] = *(const float4*)&Gx[(g * 64 + rr) * 36 + c0 + 4];
        const float4 ibv0 = *(const float4*)(ib + g * 1024 + gc);
        const float4 ibv1 = *(const float4*)(ib + g * 1024 + gc + 4);
        gv[g][0].x += ibv0.x; gv[g][0].y += ibv0.y; gv[g][0].z += ibv0.z; gv[g][0].w += ibv0.w;
        gv[g][1].x += ibv1.x; gv[g][1].y += ibv1.y; gv[g][1].z += ibv1.z; gv[g][1].w += ibv1.w;
    }
    float4 coldv[2] = { *(const float4*)(c_st + gidx), *(const float4*)(c_st + gidx + 4) };
    float4 holdv[2] = { *(const float4*)(h_in + gidx), *(const float4*)(h_in + gidx + 4) };

    float4 cw[2], hw[2];
    int4 hiv, lov;
    #pragma unroll
    for (int hf = 0; hf < 2; ++hf) {
        const float* gi = (const float*)&gv[0][hf];
        const float* gf = (const float*)&gv[1][hf];
        const float* gg = (const float*)&gv[2][hf];
        const float* go = (const float*)&gv[3][hf];
        const float* co = (const float*)&coldv[hf];
        const float* ho = (const float*)&holdv[hf];
        #pragma unroll
        for (int j = 0; j < 4; ++j) {
            float cn = sigm(gf[j]) * co[j] + sigm(gi[j]) * tanh_fast(gg[j]);
            float hn = sigm(go[j]) * tanh_fast(cn);
            float cv = upd ? cn : co[j];
            float hv = upd ? hn : ho[j];
            ((float*)&cw[hf])[j] = cv;
            ((float*)&hw[hf])[j] = hv;
            unsigned short hb, lb;
            split_bf16(hv, hb, lb);
            ((ushort_t*)&hiv)[hf * 4 + j] = hb;
            ((ushort_t*)&lov)[hf * 4 + j] = lb;
        }
    }
    *(float4*)(c_st + gidx) = cw[0];
    *(float4*)(c_st + gidx + 4) = cw[1];
    *(float4*)(h_out + gidx) = hw[0];
    *(float4*)(h_out + gidx + 4) = hw[1];
    *(int4*)(hhi_o + gidx) = hiv;
    *(int4*)(hlo_o + gidx) = lov;
}

// ---------------------------------------------------------------------------
// Generic fp32 C[M][N] = A[M][K] @ W[N][K]^T + bias[N]
// grid (M/32, N/64), block 256; per thread 4x2.
// ---------------------------------------------------------------------------
__global__ __launch_bounds__(256) void gemm_bias(
    const float* __restrict__ A, const float* __restrict__ W,
    const float* __restrict__ bias, float* __restrict__ C,
    int N, int K)
{
    __shared__ __align__(16) float As[16][32];
    __shared__ __align__(16) float Bs[16][64];
    const int tid = threadIdx.x;
    const int tm = tid & 7;
    const int tn = tid >> 3;
    const int m0 = blockIdx.x * 32, n0 = blockIdx.y * 64;
    const int am = tid >> 3;
    const int ak = (tid & 7) * 2;
    const int br = tid >> 2;
    const int bk = (tid & 3) * 4;
    const float* arow = A + (size_t)(m0 + am) * K;
    const float* brow = W + (size_t)(n0 + br) * K;
    float acc[4][2] = {};
    const int tm4 = tm * 4, tn2 = tn * 2;

    for (int k0 = 0; k0 < K; k0 += 16) {
        __syncthreads();
        float2 av = *(const float2*)(arow + k0 + ak);
        float4 bv = *(const float4*)(brow + k0 + bk);
        As[ak][am] = av.x; As[ak + 1][am] = av.y;
        Bs[bk][br] = bv.x; Bs[bk + 1][br] = bv.y;
        Bs[bk + 2][br] = bv.z; Bs[bk + 3][br] = bv.w;
        __syncthreads();
        #pragma unroll
        for (int k = 0; k < 16; ++k) {
            float4 a = *(const float4*)&As[k][tm4];
            float2 b = *(const float2*)&Bs[k][tn2];
            acc[0][0] += a.x * b.x; acc[0][1] += a.x * b.y;
            acc[1][0] += a.y * b.x; acc[1][1] += a.y * b.y;
            acc[2][0] += a.z * b.x; acc[2][1] += a.z * b.y;
            acc[3][0] += a.w * b.x; acc[3][1] += a.w * b.y;
        }
    }
    float b0 = bias[n0 + tn2], b1 = bias[n0 + tn2 + 1];
    #pragma unroll
    for (int mi = 0; mi < 4; ++mi) {
        float2 o;
        o.x = acc[mi][0] + b0;
        o.y = acc[mi][1] + b1;
        *(float2*)(C + (size_t)(m0 + tm4 + mi) * N + n0 + tn2) = o;
    }
}

// ---------------------------------------------------------------------------
// pooled[b][n] = tanh(max_e (h[4b+e] @ W_mp^T) + b_mp)   (tanh monotone)
// ---------------------------------------------------------------------------
__global__ __launch_bounds__(256) void mp_pool(
    const float* __restrict__ h, const float* __restrict__ Wmp,
    const float* __restrict__ bmp, float* __restrict__ pooled)
{
    __shared__ __align__(16) float As[16][32];
    __shared__ __align__(16) float Bs[16][64];
    const int tid = threadIdx.x;
    const int tm = tid & 7;
    const int tn = tid >> 3;
    const int m0 = blockIdx.x * 32, n0 = blockIdx.y * 64;
    const int am = tid >> 3;
    const int ak = (tid & 7) * 2;
    const int br = tid >> 2;
    const int bk = (tid & 3) * 4;
    const float* arow = h + (size_t)(m0 + am) * HH;
    const float* brow = Wmp + (size_t)(n0 + br) * HH;
    float acc[4][2] = {};
    const int tm4 = tm * 4, tn2 = tn * 2;

    for (int k0 = 0; k0 < HH; k0 += 16) {
        __syncthreads();
        float2 av = *(const float2*)(arow + k0 + ak);
        float4 bv = *(const float4*)(brow + k0 + bk);
        As[ak][am] = av.x; As[ak + 1][am] = av.y;
        Bs[bk][br] = bv.x; Bs[bk + 1][br] = bv.y;
        Bs[bk + 2][br] = bv.z; Bs[bk + 3][br] = bv.w;
        __syncthreads();
        #pragma unroll
        for (int k = 0; k < 16; ++k) {
            float4 a = *(const float4*)&As[k][tm4];
            float2 b = *(const float2*)&Bs[k][tn2];
            acc[0][0] += a.x * b.x; acc[0][1] += a.x * b.y;
            acc[1][0] += a.y * b.x; acc[1][1] += a.y * b.y;
            acc[2][0] += a.z * b.x; acc[2][1] += a.z * b.y;
            acc[3][0] += a.w * b.x; acc[3][1] += a.w * b.y;
        }
    }
    float mx0 = fmaxf(fmaxf(acc[0][0], acc[1][0]), fmaxf(acc[2][0], acc[3][0]));
    float mx1 = fmaxf(fmaxf(acc[0][1], acc[1][1]), fmaxf(acc[2][1], acc[3][1]));
    mx0 += bmp[n0 + tn2];
    mx1 += bmp[n0 + tn2 + 1];
    float2 o;
    o.x = tanh_fast(mx0);
    o.y = tanh_fast(mx1);
    const int bidx = (m0 >> 2) + tm;
    *(float2*)(pooled + (size_t)bidx * HH + n0 + tn2) = o;
}

extern "C" void kernel_launch(void* const* d_in, const int* in_sizes, int n_in,
                              void* d_out, int out_size, void* d_ws, size_t ws_size,
                              hipStream_t stream)
{
    const int*   tokens_in   = (const int*)d_in[0];
    const int*   lengths_in  = (const int*)d_in[1];
    const int*   tokens_out  = (const int*)d_in[2];
    const int*   lengths_out = (const int*)d_in[3];
    const float* embedding   = (const float*)d_in[4];
    const float* W_ih_in     = (const float*)d_in[5];
    const float* W_hh_in     = (const float*)d_in[6];
    const float* b_in        = (const float*)d_in[7];
    const float* W_ih_out    = (const float*)d_in[8];
    const float* W_hh_out    = (const float*)d_in[9];
    const float* b_out       = (const float*)d_in[10];
    const float* W_ih_p      = (const float*)d_in[11];
    const float* W_hh_p      = (const float*)d_in[12];
    const float* b_p         = (const float*)d_in[13];
    const float* W_mp        = (const float*)d_in[14];
    const float* b_mp        = (const float*)d_in[15];
    const float* W_sm        = (const float*)d_in[16];
    const float* b_sm        = (const float*)d_in[17];
    float* out = (float*)d_out;

    // workspace layout (float units); total ~18.5M floats = 74 MB
    float* ws = (float*)d_ws;
    float* h_a      = ws;                  // 524288
    float* h_b      = ws + 524288;         // 524288
    float* c_st     = ws + 1048576;        // 524288
    float* embW_in  = ws + 1572864;        // 524288
    float* embW_out = ws + 2097152;        // 524288
    float* u_p      = ws + 2621440;        // 2097152
    float* pooled   = ws + 4718592;        // 131072
    ushort_t* hhi_a = (ushort_t*)(ws + 4849664);   // 524288 bf16
    ushort_t* hlo_a = (ushort_t*)(ws + 5111808);
    ushort_t* hhi_b = (ushort_t*)(ws + 5373952);
    ushort_t* hlo_b = (ushort_t*)(ws + 5636096);
    ushort_t* Whi_in  = (ushort_t*)(ws + 5898240); // 4194304 bf16 each
    ushort_t* Wlo_in  = (ushort_t*)(ws + 7995392);
    ushort_t* Whi_out = (ushort_t*)(ws + 10092544);
    ushort_t* Wlo_out = (ushort_t*)(ws + 12189696);
    ushort_t* Whi_p   = (ushort_t*)(ws + 14286848);
    ushort_t* Wlo_p   = (ushort_t*)(ws + 16384000);

    // zero h0, c0, and h0's bf16 hi/lo (hhi_a/hlo_a are adjacent)
    fillz<<<2048, 256, 0, stream>>>(h_a, 524288);
    fillz<<<2048, 256, 0, stream>>>(c_st, 524288);
    fillz<<<2048, 256, 0, stream>>>(ws + 4849664, 524288);

    // split the three recurrent weight matrices into bf16 hi/lo
    split_w<<<16384, 256, 0, stream>>>(W_hh_in,  Whi_in,  Wlo_in,  4194304);
    split_w<<<16384, 256, 0, stream>>>(W_hh_out, Whi_out, Wlo_out, 4194304);
    split_w<<<16384, 256, 0, stream>>>(W_hh_p,   Whi_p,   Wlo_p,   4194304);

    // embW = embedding @ W_ih^T + b  (x @ W_ih collapses to a gather)
    gemm_bias<<<dim3(4, 64), 256, 0, stream>>>(embedding, W_ih_in, b_in, embW_in, 4096, 128);
    gemm_bias<<<dim3(4, 64), 256, 0, stream>>>(embedding, W_ih_out, b_out, embW_out, 4096, 128);

    float* hc = h_a;  ushort_t* hic = hhi_a;  ushort_t* loc = hlo_a;
    float* hn = h_b;  ushort_t* hin = hhi_b;  ushort_t* lon = hlo_b;

    for (int t = 0; t < 128; ++t) {
        lstm_step_mfma<<<256, 256, 0, stream>>>(
            hc, hic, loc, hn, hin, lon, c_st, Whi_in, Wlo_in, embW_in,
            tokens_in, lengths_in, t);
        float* tf = hc; hc = hn; hn = tf;
        ushort_t* th = hic; hic = hin; hin = th;
        ushort_t* tl = loc; loc = lon; lon = tl;
    }
    for (int t = 0; t < 128; ++t) {
        lstm_step_mfma<<<256, 256, 0, stream>>>(
            hc, hic, loc, hn, hin, lon, c_st, Whi_out, Wlo_out, embW_out,
            tokens_out, lengths_out, t);
        float* tf = hc; hc = hn; hn = tf;
        ushort_t* th = hic; hic = hin; hin = th;
        ushort_t* tl = loc; loc = lon; lon = tl;
    }

    // u_p = prev_h @ W_ih_p^T + b_p  (prev_h constant across all 16 steps)
    gemm_bias<<<dim3(16, 64), 256, 0, stream>>>(hc, W_ih_p, b_p, u_p, 4096, 1024);

    for (int t = 0; t < 16; ++t) {
        lstm_step_mfma<<<256, 256, 0, stream>>>(
            hc, hic, loc, hn, hin, lon, c_st, Whi_p, Wlo_p, u_p,
            nullptr, nullptr, t);
        mp_pool<<<dim3(16, 16), 256, 0, stream>>>(hn, W_mp, b_mp, pooled);
        gemm_bias<<<dim3(4, 16), 256, 0, stream>>>(pooled, W_sm, b_sm,
                                                   out + (size_t)t * (BB * PP), 1024, 1024);
        float* tf = hc; hc = hn; hn = tf;
        ushort_t* th = hic; hic = hin; hin = th;
        ushort_t* tl = loc; loc = lon; lon = tl;
    }
}